// Round 1
// 212.983 us; speedup vs baseline: 1.0176x; 1.0176x over previous
//
#include <hip/hip_runtime.h>

// Problem constants (from setup_inputs): B=32, T=512, F=513, S=3
#define BB 32
#define TT 512
#define FF 513
#define SS 3
#define NN (TT * FF)               // 262656 elements per (b, source)
#define FLOATS_PER_B (NN * SS)     // 787968 floats per batch slice (divisible by 12)
#define CHUNKS_PER_B (FLOATS_PER_B / 12)  // 65664 chunks of 12 floats (4 source-groups)
#define BLOCKS_PER_B 64            // 32 -> 64: grid 2048 blocks = 8192 waves = 100% occupancy cap
#define THREADS 256

// --- Kernel 0: zero the 288-float accumulator in workspace (poisoned 0xAA) ---
__global__ void pil_zero_ws(float* __restrict__ ws) {
    int i = threadIdx.x;
    if (i < BB * SS * SS) ws[i] = 0.0f;
}

// --- Kernel 1: accumulate sum_n |est[b,n,i] - tgt[b,n,j]| into ws[b*9+i*3+j] ---
// 8 blocks/CU (launch_bounds 2nd arg = waves/EU = blocks/CU for 256-thread blocks):
// keeps the register allocator at <=64 VGPR so all 32 waves/CU fit (currently 32 VGPR).
__global__ __launch_bounds__(THREADS, 8) void pil_partial(
        const float* __restrict__ est,
        const float* __restrict__ tgt,
        float* __restrict__ ws) {
    const int b   = blockIdx.x / BLOCKS_PER_B;
    const int blk = blockIdx.x % BLOCKS_PER_B;

    const float4* eb = (const float4*)(est + (size_t)b * FLOATS_PER_B);
    const float4* tb = (const float4*)(tgt + (size_t)b * FLOATS_PER_B);

    float acc[9];
#pragma unroll
    for (int k = 0; k < 9; ++k) acc[k] = 0.0f;

    // Each chunk c covers float4 indices 3c, 3c+1, 3c+2 => 12 floats = 4 groups of S=3.
    // CHUNKS_PER_B = 65664, stride = 16384 -> 4 iterations (+1 for 128 threads).
    for (int c = blk * THREADS + threadIdx.x; c < CHUNKS_PER_B;
         c += BLOCKS_PER_B * THREADS) {
        const float4 e0 = eb[3 * c + 0];
        const float4 e1 = eb[3 * c + 1];
        const float4 e2 = eb[3 * c + 2];
        const float4 t0 = tb[3 * c + 0];
        const float4 t1 = tb[3 * c + 1];
        const float4 t2 = tb[3 * c + 2];

        const float e[12] = {e0.x, e0.y, e0.z, e0.w, e1.x, e1.y,
                             e1.z, e1.w, e2.x, e2.y, e2.z, e2.w};
        const float t[12] = {t0.x, t0.y, t0.z, t0.w, t1.x, t1.y,
                             t1.z, t1.w, t2.x, t2.y, t2.z, t2.w};
#pragma unroll
        for (int g = 0; g < 4; ++g) {
#pragma unroll
            for (int i = 0; i < 3; ++i) {
#pragma unroll
                for (int j = 0; j < 3; ++j) {
                    acc[i * 3 + j] += fabsf(e[3 * g + i] - t[3 * g + j]);
                }
            }
        }
    }

    // Wave-level reduction (64 lanes) of each of the 9 accumulators.
#pragma unroll
    for (int k = 0; k < 9; ++k) {
        float v = acc[k];
#pragma unroll
        for (int off = 32; off > 0; off >>= 1) v += __shfl_down(v, off);
        acc[k] = v;
    }

    __shared__ float sred[THREADS / 64][9];
    const int wave = threadIdx.x >> 6;
    const int lane = threadIdx.x & 63;
    if (lane == 0) {
#pragma unroll
        for (int k = 0; k < 9; ++k) sred[wave][k] = acc[k];
    }
    __syncthreads();

    if (threadIdx.x < 9) {
        float s = 0.0f;
#pragma unroll
        for (int w = 0; w < THREADS / 64; ++w) s += sred[w][threadIdx.x];
        atomicAdd(&ws[b * 9 + threadIdx.x], s);
    }
}

// --- Kernel 2: per-b permutation losses, min over perms, mean over b ---
__global__ void pil_finalize(const float* __restrict__ ws, float* __restrict__ out) {
    const int lane = threadIdx.x;  // 64 threads, lanes >= BB idle
    float loss = 0.0f;
    if (lane < BB) {
        float C[3][3];
#pragma unroll
        for (int i = 0; i < 3; ++i)
#pragma unroll
            for (int j = 0; j < 3; ++j)
                C[i][j] = ws[lane * 9 + i * 3 + j] * (1.0f / (float)NN);

        const int P[6][3] = {{0, 1, 2}, {0, 2, 1}, {1, 0, 2},
                             {1, 2, 0}, {2, 0, 1}, {2, 1, 0}};
        float best = 3.4e38f;
#pragma unroll
        for (int p = 0; p < 6; ++p) {
            // losses[b,p] = mean_j C[b, perm[j], j]
            float l = (C[P[p][0]][0] + C[P[p][1]][1] + C[P[p][2]][2]) * (1.0f / 3.0f);
            best = fminf(best, l);
        }
        loss = best;
    }
    // Sum across the wave (lanes >= BB contribute 0), then mean over B.
#pragma unroll
    for (int off = 32; off > 0; off >>= 1) loss += __shfl_down(loss, off);
    if (lane == 0) out[0] = loss * (1.0f / (float)BB);
}

extern "C" void kernel_launch(void* const* d_in, const int* in_sizes, int n_in,
                              void* d_out, int out_size, void* d_ws, size_t ws_size,
                              hipStream_t stream) {
    const float* est = (const float*)d_in[0];
    const float* tgt = (const float*)d_in[1];
    float* ws  = (float*)d_ws;
    float* out = (float*)d_out;

    pil_zero_ws<<<1, 320, 0, stream>>>(ws);
    pil_partial<<<BB * BLOCKS_PER_B, THREADS, 0, stream>>>(est, tgt, ws);
    pil_finalize<<<1, 64, 0, stream>>>(ws, out);
}